// Round 3
// baseline (55.846 us; speedup 1.0000x reference)
//
#include <hip/hip_runtime.h>

#define THREADS 256
#define R 8                       // queries per thread (register-resident)
#define QCHUNK (THREADS * R)      // 2048 queries per block
#define TCHUNK 512                // targets staged in LDS per block

// ws layout: [0, 2*B*N) min-sqdist uint bits (fwd then bwd), then 64 float partials

__global__ __launch_bounds__(THREADS) void init_min_kernel(unsigned int* minsq, int n) {
    int i = blockIdx.x * blockDim.x + threadIdx.x;
    if (i < n) minsq[i] = 0x7F800000u;  // +inf bits
}

// For each query point, min over a chunk of target points of squared distance,
// using the expansion d2 = |p|^2 + (|g|^2 - 2 p.g); |p|^2 added after the loop.
// dir 0: query=pred, target=gt (fwd). dir 1: query=gt, target=pred (bwd).
__global__ __launch_bounds__(THREADS) void nn_min_kernel(
    const float* __restrict__ pred,   // [B,3,N]
    const float* __restrict__ gt,     // [B,3,N]
    unsigned int* __restrict__ minsq, // [2,B,N] as uint bits
    int N, int B, int nQC, int nTC, int blocksPerDir)
{
    __shared__ float4 tg[TCHUNK];     // (-2gx, -2gy, -2gz, |g|^2)

    int blk = blockIdx.x;
    int dir = blk / blocksPerDir;
    blk -= dir * blocksPerDir;
    int tc = blk % nTC;
    int qc = (blk / nTC) % nQC;
    int b  = blk / (nTC * nQC);

    const float* q = (dir ? gt : pred) + (size_t)b * 3 * N;
    const float* t = (dir ? pred : gt) + (size_t)b * 3 * N;

    int tbase = tc * TCHUNK;
    #pragma unroll
    for (int k = 0; k < TCHUNK / THREADS; ++k) {
        int j = k * THREADS + threadIdx.x;
        int gj = tbase + j;
        float gx = t[gj], gy = t[N + gj], gz = t[2 * N + gj];
        tg[j] = make_float4(-2.f * gx, -2.f * gy, -2.f * gz,
                            gx * gx + gy * gy + gz * gz);
    }
    __syncthreads();

    float px[R], py[R], pz[R], p2[R], mn[R];
    int q0 = qc * QCHUNK + threadIdx.x;
    #pragma unroll
    for (int r = 0; r < R; ++r) {
        int qi = q0 + r * THREADS;
        px[r] = q[qi];
        py[r] = q[N + qi];
        pz[r] = q[2 * N + qi];
        p2[r] = px[r] * px[r] + py[r] * py[r] + pz[r] * pz[r];
        mn[r] = 3.0e38f;
    }

    #pragma unroll 2
    for (int j = 0; j < TCHUNK; j += 2) {
        float4 ga = tg[j];
        float4 gb = tg[j + 1];
        #pragma unroll
        for (int r = 0; r < R; ++r) {
            float da = fmaf(ga.x, px[r], fmaf(ga.y, py[r], fmaf(ga.z, pz[r], ga.w)));
            float db = fmaf(gb.x, px[r], fmaf(gb.y, py[r], fmaf(gb.z, pz[r], gb.w)));
            mn[r] = fminf(fminf(da, db), mn[r]);   // fuses to v_min3_f32
        }
    }

    unsigned int* mb = minsq + ((size_t)dir * B + b) * N;
    #pragma unroll
    for (int r = 0; r < R; ++r) {
        float d2 = fmaxf(mn[r] + p2[r], 0.f);  // clamp: keep uint-bit ordering valid
        atomicMin(&mb[q0 + r * THREADS], __float_as_uint(d2));
    }
}

// Stage 1: 64 blocks x 256 threads -> 64 partial sums of sqrt(min+eps)
__global__ __launch_bounds__(THREADS) void reduce1_kernel(
    const unsigned int* __restrict__ minsq, float* __restrict__ partials, int total)
{
    __shared__ float sdata[THREADS];
    float s = 0.f;
    for (int i = blockIdx.x * THREADS + threadIdx.x; i < total; i += gridDim.x * THREADS) {
        float v = __uint_as_float(minsq[i]);
        s += sqrtf(v + 1e-8f);
    }
    sdata[threadIdx.x] = s;
    __syncthreads();
    for (int off = THREADS / 2; off > 0; off >>= 1) {
        if (threadIdx.x < off) sdata[threadIdx.x] += sdata[threadIdx.x + off];
        __syncthreads();
    }
    if (threadIdx.x == 0) partials[blockIdx.x] = sdata[0];
}

// Stage 2: one wave reduces 64 partials.
__global__ __launch_bounds__(64) void reduce2_kernel(
    const float* __restrict__ partials, float* __restrict__ out, float inv)
{
    float s = partials[threadIdx.x];
    #pragma unroll
    for (int off = 32; off > 0; off >>= 1) s += __shfl_down(s, off);
    if (threadIdx.x == 0) out[0] = s * inv;
}

extern "C" void kernel_launch(void* const* d_in, const int* in_sizes, int n_in,
                              void* d_out, int out_size, void* d_ws, size_t ws_size,
                              hipStream_t stream) {
    const float* pred = (const float*)d_in[0];
    const float* gt   = (const float*)d_in[1];
    const int N = 8192;
    const int B = in_sizes[0] / (3 * N);   // = 4

    unsigned int* minsq = (unsigned int*)d_ws;            // 2*B*N uints = 256 KB
    int total = 2 * B * N;
    float* partials = (float*)(minsq + total);            // 64 floats

    init_min_kernel<<<(total + THREADS - 1) / THREADS, THREADS, 0, stream>>>(minsq, total);

    int nQC = N / QCHUNK;             // 4
    int nTC = N / TCHUNK;             // 16
    int blocksPerDir = B * nQC * nTC; // 256
    nn_min_kernel<<<2 * blocksPerDir, THREADS, 0, stream>>>(
        pred, gt, minsq, N, B, nQC, nTC, blocksPerDir);

    reduce1_kernel<<<64, THREADS, 0, stream>>>(minsq, partials, total);
    reduce2_kernel<<<1, 64, 0, stream>>>(partials, (float*)d_out, 1.0f / (B * N));
}

// Round 4
// 51.805 us; speedup vs baseline: 1.0780x; 1.0780x over previous
//
#include <hip/hip_runtime.h>

#define THREADS 256
#define R 4                       // queries per thread (register-resident)
#define QCHUNK (THREADS * R)      // 1024 queries per block
#define TCHUNK 256                // targets staged in LDS per block

// ws layout: [0, 2*B*N) min-sqdist uint bits (fwd then bwd), then 64 float partials

__global__ __launch_bounds__(THREADS) void init_min_kernel(unsigned int* minsq, int n) {
    int i = blockIdx.x * blockDim.x + threadIdx.x;
    if (i < n) minsq[i] = 0x7F800000u;  // +inf bits
}

// For each query point, min over a chunk of target points of squared distance,
// using the expansion d2 = |p|^2 + (|g|^2 - 2 p.g); |p|^2 added after the loop.
// dir 0: query=pred, target=gt (fwd). dir 1: query=gt, target=pred (bwd).
__global__ __launch_bounds__(THREADS) void nn_min_kernel(
    const float* __restrict__ pred,   // [B,3,N]
    const float* __restrict__ gt,     // [B,3,N]
    unsigned int* __restrict__ minsq, // [2,B,N] as uint bits
    int N, int B, int nQC, int nTC, int blocksPerDir)
{
    __shared__ float4 tg[TCHUNK];     // (-2gx, -2gy, -2gz, |g|^2)

    int blk = blockIdx.x;
    int dir = blk / blocksPerDir;
    blk -= dir * blocksPerDir;
    int tc = blk % nTC;
    int qc = (blk / nTC) % nQC;
    int b  = blk / (nTC * nQC);

    const float* q = (dir ? gt : pred) + (size_t)b * 3 * N;
    const float* t = (dir ? pred : gt) + (size_t)b * 3 * N;

    int tbase = tc * TCHUNK;
    {
        int j = threadIdx.x;              // TCHUNK == THREADS
        int gj = tbase + j;
        float gx = t[gj], gy = t[N + gj], gz = t[2 * N + gj];
        tg[j] = make_float4(-2.f * gx, -2.f * gy, -2.f * gz,
                            gx * gx + gy * gy + gz * gz);
    }

    float px[R], py[R], pz[R], p2[R], mn[R];
    int q0 = qc * QCHUNK + threadIdx.x;
    #pragma unroll
    for (int r = 0; r < R; ++r) {
        int qi = q0 + r * THREADS;
        px[r] = q[qi];
        py[r] = q[N + qi];
        pz[r] = q[2 * N + qi];
        p2[r] = px[r] * px[r] + py[r] * py[r] + pz[r] * pz[r];
        mn[r] = 3.0e38f;
    }
    __syncthreads();

    // Software-pipelined: prefetch next j-pair into registers, compute current.
    float4 ga = tg[0], gb = tg[1];
    #pragma unroll 4
    for (int j = 0; j < TCHUNK; j += 2) {
        int jn = (j + 2) & (TCHUNK - 1);   // wraps on last iter; values unused
        float4 gc = tg[jn];
        float4 gd = tg[jn + 1];
        #pragma unroll
        for (int r = 0; r < R; ++r) {
            float da = fmaf(ga.x, px[r], fmaf(ga.y, py[r], fmaf(ga.z, pz[r], ga.w)));
            float db = fmaf(gb.x, px[r], fmaf(gb.y, py[r], fmaf(gb.z, pz[r], gb.w)));
            mn[r] = fminf(fminf(da, db), mn[r]);   // fuses to v_min3_f32
        }
        ga = gc; gb = gd;
    }

    unsigned int* mb = minsq + ((size_t)dir * B + b) * N;
    #pragma unroll
    for (int r = 0; r < R; ++r) {
        float d2 = fmaxf(mn[r] + p2[r], 0.f);  // clamp: keep uint-bit ordering valid
        atomicMin(&mb[q0 + r * THREADS], __float_as_uint(d2));
    }
}

// Stage 1: 64 blocks x 256 threads -> 64 partial sums of sqrt(min+eps)
__global__ __launch_bounds__(THREADS) void reduce1_kernel(
    const unsigned int* __restrict__ minsq, float* __restrict__ partials, int total)
{
    __shared__ float sdata[THREADS];
    float s = 0.f;
    for (int i = blockIdx.x * THREADS + threadIdx.x; i < total; i += gridDim.x * THREADS) {
        float v = __uint_as_float(minsq[i]);
        s += sqrtf(v + 1e-8f);
    }
    sdata[threadIdx.x] = s;
    __syncthreads();
    for (int off = THREADS / 2; off > 0; off >>= 1) {
        if (threadIdx.x < off) sdata[threadIdx.x] += sdata[threadIdx.x + off];
        __syncthreads();
    }
    if (threadIdx.x == 0) partials[blockIdx.x] = sdata[0];
}

// Stage 2: one wave reduces 64 partials.
__global__ __launch_bounds__(64) void reduce2_kernel(
    const float* __restrict__ partials, float* __restrict__ out, float inv)
{
    float s = partials[threadIdx.x];
    #pragma unroll
    for (int off = 32; off > 0; off >>= 1) s += __shfl_down(s, off);
    if (threadIdx.x == 0) out[0] = s * inv;
}

extern "C" void kernel_launch(void* const* d_in, const int* in_sizes, int n_in,
                              void* d_out, int out_size, void* d_ws, size_t ws_size,
                              hipStream_t stream) {
    const float* pred = (const float*)d_in[0];
    const float* gt   = (const float*)d_in[1];
    const int N = 8192;
    const int B = in_sizes[0] / (3 * N);   // = 4

    unsigned int* minsq = (unsigned int*)d_ws;            // 2*B*N uints = 256 KB
    int total = 2 * B * N;
    float* partials = (float*)(minsq + total);            // 64 floats

    init_min_kernel<<<(total + THREADS - 1) / THREADS, THREADS, 0, stream>>>(minsq, total);

    int nQC = N / QCHUNK;              // 8
    int nTC = N / TCHUNK;              // 32
    int blocksPerDir = B * nQC * nTC;  // 1024
    nn_min_kernel<<<2 * blocksPerDir, THREADS, 0, stream>>>(
        pred, gt, minsq, N, B, nQC, nTC, blocksPerDir);

    reduce1_kernel<<<64, THREADS, 0, stream>>>(minsq, partials, total);
    reduce2_kernel<<<1, 64, 0, stream>>>(partials, (float*)d_out, 1.0f / (B * N));
}